// Round 8
// baseline (276.558 us; speedup 1.0000x reference)
//
#include <hip/hip_runtime.h>
#include <math.h>

#ifndef M_PI
#define M_PI 3.14159265358979323846
#endif

// ---------------- workspace layout (float offsets) ----------------
#define OFF_TRIG 708              // float2 cs32[32] then cs64[64]  (192 floats)
#define OFF_D1F 900               // [16][64][31]                 31744
#define OFF_D1I 32644             // D1IT: [j=32][mm=16][l=16][nh=32]  262144 (mh>=15 half only)
#define OFF_D2F 294788            // D2FT: [j=32][pq=225][l=8]    57600
#define OFF_S2  352388            // [8][15][15]                   1800
#define OFF_XH  354188            // float2 [16][16*31]           15872 floats
#define OFF_XMN 370060            // float2 [16][32][32][225]   7372800 floats
#define OFF_U   7742860           // float2 [16*32][8][225]     1843200 floats
#define OFF_FEAT 9586060          // [16][64]                      1024 floats
#define OFF_SENT 9587084          // 2 x u32 sentinel (tables built)

typedef float v2f __attribute__((ext_vector_type(2)));
typedef float v4f __attribute__((ext_vector_type(4)));

static __device__ __forceinline__ int iabs_(int v) { return v < 0 ? -v : v; }

static __device__ __forceinline__ v2f mkv2(float a, float b) {
    v2f r; r.x = a; r.y = b; return r;
}
static __device__ __forceinline__ v2f ldv2(float2 a) { return mkv2(a.x, a.y); }

static __device__ __forceinline__ double powi_d(double x, int e) {
    double r = 1.0;
    while (e) { if (e & 1) r *= x; x *= x; e >>= 1; }
    return r;
}

// ---------------- K0a: tiny table precompute (1 block) + feat zero ----------------
__global__ __launch_bounds__(256) void k0a_tables(float* __restrict__ ws) {
    int t = threadIdx.x;
    for (int i = t; i < 1024; i += 256) ws[OFF_FEAT + i] = 0.f;   // feat zero (always)
    const unsigned* wsu = (const unsigned*)ws;
    if (wsu[OFF_SENT] == 0x1CEB00DAu && wsu[OFF_SENT + 1] == 0x0DDBA11u) return;

    double* T = (double*)ws;
    __shared__ double lg[64];
    if (t < 64) lg[t] = (t == 0) ? 0.0 : log((double)t);
    __syncthreads();
    if (t == 0) {
        double s = 0.0;
        for (int i = 0; i < 64; ++i) { s += lg[i]; T[i] = s; }   // LF[i]=log(i!)
    }
    if (t < 64) {
        double beta = M_PI * (2.0 * t + 1.0) / 128.0;
        double s = 0.0;
        for (int k = 0; k < 32; ++k) s += sin((2.0 * k + 1.0) * beta) / (2.0 * k + 1.0);
        T[64 + t] = 2.0 / 32.0 * sin(beta) * s;
        T[160 + t] = cos(0.5 * beta);
        T[224 + t] = sin(0.5 * beta);
    }
    if (t >= 64 && t < 96) {
        int j = t - 64;
        double beta = M_PI * (2.0 * j + 1.0) / 64.0;
        double s = 0.0;
        for (int k = 0; k < 16; ++k) s += sin((2.0 * k + 1.0) * beta) / (2.0 * k + 1.0);
        T[128 + j] = 2.0 / 16.0 * sin(beta) * s;
        T[288 + j] = cos(0.5 * beta);
        T[320 + j] = sin(0.5 * beta);
    }
    if (t == 96) {
        T[352] = cos(M_PI / 64.0);
        T[353] = sin(M_PI / 64.0);
    }
    float2* F = (float2*)(ws + OFF_TRIG);
    if (t < 32) {
        double a = 2.0 * M_PI * (double)t / 32.0;
        F[t] = make_float2((float)cos(a), (float)sin(a));
    }
    if (t >= 128 && t < 192) {
        int i = t - 128;
        double a = 2.0 * M_PI * (double)i / 64.0;
        F[32 + i] = make_float2((float)cos(a), (float)sin(a));
    }
}

// ---------------- K0: build Wigner constant tables ----------------
// Divide-free k-loop: reciprocals from a per-block LDS table.
__device__ double wig_fast(int l, int m, int n, double cb, double sb,
                           const double* LF, const double* INV) {
    int kmin = max(0, m - n), kmax = min(l + m, l - n);
    if (kmax < kmin) return 0.0;
    double lc = 0.5 * (LF[l + m] + LF[l - m] + LF[l + n] + LF[l - n])
              - LF[kmin] - LF[l + m - kmin] - LF[l - n - kmin] - LF[n - m + kmin];
    double t = exp(lc) * powi_d(cb, 2 * l + m - n - 2 * kmin)
                       * powi_d(sb, n - m + 2 * kmin);
    if (kmin & 1) t = -t;
    double ratio = (sb * sb) / (cb * cb);
    double s = t;
    for (int k = kmin; k < kmax; ++k) {
        double num = (double)((l + m - k) * (l - n - k));
        t *= -num * INV[k + 1] * INV[n - m + k + 1] * ratio;
        s += t;
    }
    return s;
}

// D1IT now stores ONLY the mh>=15 half used by k2: [j][mm=mh-15][l][nh32].
// Total elements: 31744 (D1F) + 262144 (D1IT) + 57600 (D2FT) + 1800 (S2) = 353288.
__global__ __launch_bounds__(256) void k0_consts(float* __restrict__ ws) {
    const unsigned* wsu = (const unsigned*)ws;
    if (wsu[OFF_SENT] == 0x1CEB00DAu && wsu[OFF_SENT + 1] == 0x0DDBA11u) return;

    const double* T = (const double*)ws;
    __shared__ double LF[64];
    __shared__ double INV[64];
    int tid = threadIdx.x;
    if (tid < 64) {
        LF[tid] = T[tid];
        INV[tid] = (tid == 0) ? 0.0 : 1.0 / (double)tid;
    }
    __syncthreads();
    int gid = blockIdx.x * 256 + tid;
    if (gid >= 353288) return;

    if (gid < 31744) {                       // D1F [l][j][mh]
        int mh = gid % 31, j = (gid / 31) % 64, l = gid / (31 * 64);
        int m = mh - 15;
        double v = 0.0;
        if (iabs_(m) <= l)
            v = T[64 + j] * wig_fast(l, m, 0, T[160 + j], T[224 + j], LF, INV);
        ws[OFF_D1F + gid] = (float)v;
    } else if (gid < 293888) {               // D1IT [j][mm][l][nh32], m = mm >= 0
        int r = gid - 31744;
        int nh = r & 31;
        int l  = (r >> 5) & 15;
        int mm = (r >> 9) & 15;
        int j  = r >> 13;
        int n = nh - 15;
        double v = 0.0;
        if (nh < 31 && mm <= l && iabs_(n) <= l)
            v = (2.0 * l + 1.0) * wig_fast(l, mm, n, T[288 + j], T[320 + j], LF, INV);
        ws[OFF_D1I + r] = (float)v;
    } else if (gid < 351488) {               // D2FT [j][pq][l]
        int r = gid - 293888;
        int l = r & 7;
        int pq = (r >> 3) % 225;
        int j = r / 1800;
        int mh = pq / 15, nh = pq % 15;
        int m = mh - 7, n = nh - 7;
        double v = 0.0;
        if (iabs_(m) <= l && iabs_(n) <= l)
            v = T[128 + j] * wig_fast(l, m, n, T[288 + j], T[320 + j], LF, INV);
        ws[OFF_D2F + r] = (float)v;
    } else {                                 // S2 = D2I[:,0,:,:]
        int r = gid - 351488;
        int nh = r % 15, mh = (r / 15) % 15, l = r / 225;
        int m = mh - 7, n = nh - 7;
        double v = 0.0;
        if (iabs_(m) <= l && iabs_(n) <= l)
            v = (2.0 * l + 1.0) * wig_fast(l, m, n, T[352], T[353], LF, INV);
        ws[OFF_S2 + r] = (float)v;
    }
}

// ---------------- K1: x -> xm -> xh (also sets the tables sentinel) ----------------
__global__ __launch_bounds__(256) void k1_xh(const float* __restrict__ x,
                                             float* __restrict__ ws,
                                             float2* __restrict__ xh) {
    __shared__ float  xs[64 * 64];
    __shared__ float2 xm[64 * 8];
    __shared__ float2 cs64[64];
    int c = blockIdx.x, b = blockIdx.y, tid = threadIdx.x;
    if (c == 0 && b == 0 && tid == 0) {      // tables valid from here on
        unsigned* wsu = (unsigned*)ws;
        wsu[OFF_SENT] = 0x1CEB00DAu;
        wsu[OFF_SENT + 1] = 0x0DDBA11u;
    }
    int mh0 = c * 8;
    int cnt = min(8, 31 - mh0);
    for (int i = tid; i < 4096; i += 256) xs[i] = x[b * 4096 + i];
    if (tid < 64) cs64[tid] = ((const float2*)(ws + OFF_TRIG))[32 + tid];
    __syncthreads();
    for (int i = tid; i < 512; i += 256) {
        int j = i >> 3, mi = i & 7;
        if (mi < cnt) {
            int mu = mh0 + mi - 15;
            float re = 0.f, im = 0.f;
            for (int t = 0; t < 64; ++t) {
                float2 w = cs64[(mu * t) & 63];
                float xv = xs[j * 64 + t];
                re += xv * w.x;
                im -= xv * w.y;
            }
            xm[i] = make_float2(re, im);
        }
    }
    __syncthreads();
    const float* D1F = ws + OFF_D1F;
    if (tid < 128) {
        int l = tid >> 3, mi = tid & 7;
        if (mi < cnt) {
            int mh = mh0 + mi;
            float re = 0.f, im = 0.f;
            for (int j = 0; j < 64; ++j) {
                float d = D1F[(l * 64 + j) * 31 + mh];
                float2 v = xm[j * 8 + mi];
                re += d * v.x;
                im += d * v.y;
            }
            xh[b * 496 + l * 31 + mh] = make_float2(re, im);
        }
    }
}

// ------- K2: per-(b,f,j) plane; grid reordered (b fastest, j slowest) so
// concurrently-resident blocks share one D1IT j-slab -> L2-resident table.
// Math identical to the verified 82us version. -------
__global__ __launch_bounds__(256) void k2_planes(const float* __restrict__ w1r,
                                                 const float* __restrict__ w1i,
                                                 const float* __restrict__ ws,
                                                 float2* __restrict__ xmn) {
    __shared__ char ar[13568];
    __shared__ float2 cs2[32];              // (c, s) for e^{2pi i k/32}
    float2* As  = (float2*)ar;              // 496 f2 [0,3968)      (f1 phase)
    float2* Wv  = (float2*)(ar + 4096);     // 512 f2 [4096,8192)   (f1 phase)
    float2* fH  = (float2*)(ar + 8192);     // 16 x 34 f2 [8192,12544) (f1 -> FC)
    float2* FC  = (float2*)ar;              // 4 x 146 f2 [0,4672)  (FC -> t)
    float2* tls = (float2*)(ar + 4672);     // 17 x 34 f2 [4672,9296) (t -> ss)
    float*  ssb = (float*)(ar + 9296);      // 32 x 33 f [9296,13520) (ss -> gg)
    float2* gg  = (float2*)ar;              // 32 x 18 f2 [0,4608)  (gg -> combos)
    float2* Cc  = (float2*)(ar + 4864);     // 4 x 152 f2 [4864,9728) (combos -> h)

    int b = blockIdx.x, f = blockIdx.y, j = blockIdx.z;
    int tid = threadIdx.x;
    const float2* xh = (const float2*)(ws + OFF_XH);

    if (tid < 32) cs2[tid] = ((const float2*)(ws + OFF_TRIG))[tid];
    for (int i = tid; i < 496; i += 256) As[i] = xh[b * 496 + i];
    // V[l,nh] = 0.5*mask*( conj(w1[l,nh]) + (-1)^(nh-15) * w1[l,30-nh] )
    for (int i = tid; i < 512; i += 256) {
        int l = i >> 5, nh = i & 31;
        bool val = (nh < 31 && iabs_(nh - 15) <= l);
        int nhc = val ? nh : 15;
        int base = f * 496 + l * 31;
        float wr1 = w1r[base + nhc], wi1 = w1i[base + nhc];
        float wr2 = w1r[base + 30 - nhc], wi2 = w1i[base + 30 - nhc];
        float s = (nh & 1) ? 1.f : -1.f;
        float vr = 0.5f * (wr1 + s * wr2);
        float vi = 0.5f * (-wi1 + s * wi2);
        Wv[i] = val ? make_float2(vr, vi) : make_float2(0.f, 0.f);
    }
    __syncthreads();
    // ---- fH[mm, nh] = sum_l D1IT[j,mm,l,nh] * A[l,mm+15] * V[l,nh], mm=0..15 ----
    if (tid < 128) {
        int mm = tid >> 3;
        int nh0 = (tid & 7) * 4;
        int mrow = mm + 15;
        v2f a0 = {0.f, 0.f}, a1 = {0.f, 0.f}, a2 = {0.f, 0.f}, a3 = {0.f, 0.f};
        const float* Dbase = ws + OFF_D1I + ((j * 16 + mm) * 16) * 32 + nh0;
        for (int l = mm; l < 16; ++l) {
            float2 a = As[l * 31 + mrow];
            v4f w01 = *(const v4f*)(Wv + l * 32 + nh0);
            v4f w23 = *(const v4f*)(Wv + l * 32 + nh0 + 2);
            v4f d = *(const v4f*)(Dbase + l * 32);
            v2f w, p;
            w = w01.xy; p = a.x * w + a.y * mkv2(-w.y, w.x); a0 += d.x * p;
            w = w01.zw; p = a.x * w + a.y * mkv2(-w.y, w.x); a1 += d.y * p;
            w = w23.xy; p = a.x * w + a.y * mkv2(-w.y, w.x); a2 += d.z * p;
            w = w23.zw; p = a.x * w + a.y * mkv2(-w.y, w.x); a3 += d.w * p;
        }
        float2* fr = fH + mm * 34 + nh0;
        fr[0] = make_float2(a0.x, a0.y);
        fr[1] = make_float2(a1.x, a1.y);
        fr[2] = make_float2(a2.x, a2.y);
        fr[3] = make_float2(a3.x, a3.y);
    }
    __syncthreads();
    // ---- FC_r[mm,n0] = sum_k i^{kr} fH[mm, n0+8k]  (radix-4 input combos) ----
    if (tid < 128) {
        int mm = tid >> 3, n0 = tid & 7;
        const float2* frow = fH + mm * 34 + n0;
        v2f f0 = ldv2(frow[0]), g1 = ldv2(frow[8]), g2 = ldv2(frow[16]), g3 = ldv2(frow[24]);
        v2f E = f0 + g2, F = f0 - g2, G = g1 + g3, H = g1 - g3;
        int base = mm * 9 + n0;
        FC[0 * 146 + base] = make_float2(E.x + G.x, E.y + G.y);   // r=0: E+G
        FC[1 * 146 + base] = make_float2(F.x - H.y, F.y + H.x);   // r=1: F+iH
        FC[2 * 146 + base] = make_float2(E.x - G.x, E.y - G.y);   // r=2: E-G
        FC[3 * 146 + base] = make_float2(F.x + H.y, F.y - H.x);   // r=3: F-iH
    }
    __syncthreads();
    // ---- t[mm, v0+8k'] via S'_r from FC combos ----
    if (tid < 128) {
        int mm = tid >> 3, v0 = tid & 7;
        const float2* fc = FC + (v0 & 3) * 146 + mm * 9;
        v2f S0 = {0.f,0.f}, S1 = {0.f,0.f}, S2 = {0.f,0.f}, S3 = {0.f,0.f};
        v2f w = ldv2(cs2[(17 * v0) & 31]);    // w^{-15 v0}
        v2f st = ldv2(cs2[v0]);               // step w^{v0}
        {
            v2f fv;
            fv = ldv2(fc[0]); S1 += fv.x * w + fv.y * mkv2(-w.y, w.x);
            w = w.x * st + w.y * mkv2(-st.y, st.x);
            fv = ldv2(fc[1]); S2 += fv.x * w + fv.y * mkv2(-w.y, w.x);
            w = w.x * st + w.y * mkv2(-st.y, st.x);
            fv = ldv2(fc[2]); S3 += fv.x * w + fv.y * mkv2(-w.y, w.x);
            w = w.x * st + w.y * mkv2(-st.y, st.x);
            fv = ldv2(fc[3]); S0 += fv.x * w + fv.y * mkv2(-w.y, w.x);
            w = w.x * st + w.y * mkv2(-st.y, st.x);
            fv = ldv2(fc[4]); S1 += fv.x * w + fv.y * mkv2(-w.y, w.x);
            w = w.x * st + w.y * mkv2(-st.y, st.x);
            fv = ldv2(fc[5]); S2 += fv.x * w + fv.y * mkv2(-w.y, w.x);
            w = w.x * st + w.y * mkv2(-st.y, st.x);
            fv = ldv2(fc[6]); S3 += fv.x * w + fv.y * mkv2(-w.y, w.x);
            w = w.x * st + w.y * mkv2(-st.y, st.x);
            fv = ldv2(fc[7]); S0 += fv.x * w + fv.y * mkv2(-w.y, w.x);
        }
        v2f E = S0 + S2, F = S0 - S2, G = S1 + S3, H = S1 - S3;
        v2f A0 = E + G, A2 = E - G;
        v2f iH = mkv2(-H.y, H.x);
        v2f A1 = F + iH, A3 = F - iH;
        float2* trow = tls + mm * 34;
        trow[v0]      = make_float2(A0.x, A0.y);
        trow[v0 + 8]  = make_float2(A1.x, A1.y);
        trow[v0 + 16] = make_float2(A2.x, A2.y);
        trow[v0 + 24] = make_float2(A3.x, A3.y);
    } else if (tid < 162) {
        tls[16 * 34 + (tid - 128)] = make_float2(0.f, 0.f);   // zero row 16
    }
    __syncthreads();
    // ---- ss[u,v] = relu( t[0,v].re + 2 sum_{m=1..15} Re(t[m,v] e^{imu th}) ) ----
    {
        int v = tid & 31, u0 = tid >> 5;
        v2f Z0 = {0.f,0.f}, Z1 = {0.f,0.f}, Z2 = {0.f,0.f}, Z3 = {0.f,0.f};
        v2f y1 = ldv2(cs2[u0]);
        v2f y2 = ldv2(cs2[(2 * u0) & 31]);
        v2f y3 = ldv2(cs2[(3 * u0) & 31]);
        v2f y4 = ldv2(cs2[(4 * u0) & 31]);
        v2f st = y4;                          // step e^{i 4 u0 th}
#pragma unroll
        for (int mb = 1; mb <= 13; mb += 4) {
            float2 tv;
            tv = tls[mb * 34 + v];
            Z1 += tv.x * y1; Z1 += tv.y * mkv2(-y1.y, y1.x);
            tv = tls[(mb + 1) * 34 + v];
            Z2 += tv.x * y2; Z2 += tv.y * mkv2(-y2.y, y2.x);
            tv = tls[(mb + 2) * 34 + v];
            Z3 += tv.x * y3; Z3 += tv.y * mkv2(-y3.y, y3.x);
            tv = tls[(mb + 3) * 34 + v];
            Z0 += tv.x * y4; Z0 += tv.y * mkv2(-y4.y, y4.x);
            y1 = y1.x * st + y1.y * mkv2(-st.y, st.x);
            y2 = y2.x * st + y2.y * mkv2(-st.y, st.x);
            y3 = y3.x * st + y3.y * mkv2(-st.y, st.x);
            y4 = y4.x * st + y4.y * mkv2(-st.y, st.x);
        }
        float E = Z0.x + Z2.x, F = Z0.x - Z2.x;
        float G = Z1.x + Z3.x;
        float Hy = Z1.y - Z3.y;
        float s0 = E + G, s2 = E - G;
        float s1 = F - Hy, s3 = F + Hy;
        float t0x = tls[v].x;
        ssb[u0 * 33 + v]        = fmaxf(t0x + 2.f * s0, 0.f);
        ssb[(u0 + 8) * 33 + v]  = fmaxf(t0x + 2.f * s1, 0.f);
        ssb[(u0 + 16) * 33 + v] = fmaxf(t0x + 2.f * s2, 0.f);
        ssb[(u0 + 24) * 33 + v] = fmaxf(t0x + 2.f * s3, 0.f);
    }
    __syncthreads();
    // ---- gg[u,q'] = sum_v ss[u,v] e^{-i q' v th}, radix-4 over v ----
    {
        int u = tid >> 3, q = tid & 7;
        int qm = q & 3;
        float r1 = (qm == 0) ? 1.f : (qm == 2 ? -1.f : 0.f);
        float r2 = (qm & 1) ? -1.f : 1.f;
        float i1 = (qm == 1) ? -1.f : (qm == 3 ? 1.f : 0.f);
        v2f g = {0.f, 0.f};
        const float* srow = ssb + u * 33;
        v2f w = mkv2(1.f, 0.f);
        v2f st = ldv2(cs2[(32 - q) & 31]);    // step e^{-i q th}
#pragma unroll
        for (int vb = 0; vb < 8; ++vb) {
            float s0 = srow[vb], s1 = srow[vb + 8], s2 = srow[vb + 16], s3 = srow[vb + 24];
            float zre = (s0 + r2 * s2) + r1 * (s1 + s3);
            float zim = i1 * (s1 - s3);
            g += zre * w; g += zim * mkv2(-w.y, w.x);
            w = w.x * st + w.y * mkv2(-st.y, st.x);
        }
        gg[u * 18 + 7 + q] = make_float2(g.x, g.y);
        if (q) gg[u * 18 + 7 - q] = make_float2(g.x, -g.y);
    }
    __syncthreads();
    // ---- C_r[u0,qh] = sum_k i^{-rk} gg[u0+8k, qh]  (radix-4 over u) ----
    if (tid < 120) {
        int u0 = tid / 15, qh = tid % 15;
        v2f g0 = ldv2(gg[u0 * 18 + qh]);
        v2f g1 = ldv2(gg[(u0 + 8) * 18 + qh]);
        v2f g2 = ldv2(gg[(u0 + 16) * 18 + qh]);
        v2f g3 = ldv2(gg[(u0 + 24) * 18 + qh]);
        v2f E = g0 + g2, F = g0 - g2, G = g1 + g3, H = g1 - g3;
        int base = u0 * 19 + qh;
        Cc[0 * 152 + base] = make_float2(E.x + G.x, E.y + G.y);   // r=0: E+G
        Cc[1 * 152 + base] = make_float2(F.x + H.y, F.y - H.x);   // r=1: F-iH
        Cc[2 * 152 + base] = make_float2(E.x - G.x, E.y - G.y);   // r=2: E-G
        Cc[3 * 152 + base] = make_float2(F.x - H.y, F.y + H.x);   // r=3: F+iH
    }
    __syncthreads();
    // ---- h[p,q] = sum_{u0} C_{p&3}[u0,q] e^{-i p u0 th};  h[-p,-q] = conj ----
    if (tid < 113) {
        int ph, qh;
        if (tid < 105) { ph = 8 + tid / 15; qh = tid % 15; }
        else           { ph = 7; qh = 7 + (tid - 105); }
        int p = ph - 7;
        const float2* cp = Cc + (p & 3) * 152 + qh;
        v2f h = {0.f, 0.f};
        v2f w = mkv2(1.f, 0.f);
        v2f st = ldv2(cs2[(32 - p) & 31]);    // step e^{-i p th}
#pragma unroll
        for (int u0 = 0; u0 < 8; ++u0) {
            v2f gv = ldv2(cp[u0 * 19]);
            h += gv.x * w + gv.y * mkv2(-w.y, w.x);
            w = w.x * st + w.y * mkv2(-st.y, st.x);
        }
        float2* outp = xmn + ((size_t)((b * 32 + f) * 32 + j)) * 225;
        outp[ph * 15 + qh] = make_float2(h.x, h.y);
        if (ph > 7 || qh > 7)
            outp[(14 - ph) * 15 + (14 - qh)] = make_float2(h.x, -h.y);
    }
}

// ---------- K34: fused xh2 + U, block per (b,c); packed-fp32 MACs ----------
__global__ __launch_bounds__(256) void k34_U(const float* __restrict__ ws,
                                             const float2* __restrict__ xmn,
                                             float2* __restrict__ U) {
    __shared__ float2 xh2s[1800];
    __shared__ float  S2s[1800];
    int bc = blockIdx.x, tid = threadIdx.x;

    for (int i = tid; i < 1800; i += 256) S2s[i] = ws[OFF_S2 + i];

    v2f a0 = {0.f,0.f}, a1 = {0.f,0.f}, a2 = {0.f,0.f}, a3 = {0.f,0.f};
    v2f a4 = {0.f,0.f}, a5 = {0.f,0.f}, a6 = {0.f,0.f}, a7 = {0.f,0.f};
    if (tid < 225) {
        const float2* xp = xmn + (size_t)bc * 7200;
        const v4f* dw = (const v4f*)(ws + OFF_D2F);
        for (int j = 0; j < 32; ++j) {
            float2 xvf = xp[j * 225 + tid];
            v2f xv = mkv2(xvf.x, xvf.y);
            v4f dA = dw[(j * 225 + tid) * 2];
            v4f dB = dw[(j * 225 + tid) * 2 + 1];
            a0 += dA.x * xv; a1 += dA.y * xv; a2 += dA.z * xv; a3 += dA.w * xv;
            a4 += dB.x * xv; a5 += dB.y * xv; a6 += dB.z * xv; a7 += dB.w * xv;
        }
        xh2s[0 * 225 + tid] = make_float2(a0.x, a0.y);
        xh2s[1 * 225 + tid] = make_float2(a1.x, a1.y);
        xh2s[2 * 225 + tid] = make_float2(a2.x, a2.y);
        xh2s[3 * 225 + tid] = make_float2(a3.x, a3.y);
        xh2s[4 * 225 + tid] = make_float2(a4.x, a4.y);
        xh2s[5 * 225 + tid] = make_float2(a5.x, a5.y);
        xh2s[6 * 225 + tid] = make_float2(a6.x, a6.y);
        xh2s[7 * 225 + tid] = make_float2(a7.x, a7.y);
    }
    __syncthreads();

    for (int idx = tid; idx < 1800; idx += 256) {
        int l = idx / 225;
        int rem = idx - l * 225;
        int n = rem / 15, k = rem - n * 15;
        v2f a = {0.f, 0.f};
        for (int m = 0; m < 15; ++m) {
            float s = S2s[(l * 15 + m) * 15 + n];
            float2 vf = xh2s[l * 225 + m * 15 + k];
            a += s * mkv2(vf.x, vf.y);
        }
        U[(size_t)bc * 1800 + idx] = make_float2(a.x, a.y);
    }
}

// ---------- K5: block per (c,l,fc); W staged in LDS (28.9KB), U streamed ----------
__global__ __launch_bounds__(256) void k5_feat(const float* __restrict__ w2r,
                                               const float* __restrict__ w2i,
                                               const float2* __restrict__ U,
                                               float* __restrict__ feat) {
    __shared__ float2 Wsh[16 * 226];         // 28928 B -> 4-5 blocks/CU
    int bx = blockIdx.x;
    int c = bx >> 5, l = (bx >> 2) & 7, fc = bx & 3;
    int tid = threadIdx.x;

    for (int i = tid; i < 3600; i += 256) {
        int fr = i / 225;
        int f = fc * 16 + fr;
        int t = i - fr * 225;
        int n = t / 15, k = t - n * 15;
        bool valid = (iabs_(n - 7) <= l) && (iabs_(k - 7) <= l);
        int wi = ((c * 64 + f) * 8 + l) * 225 + t;
        Wsh[fr * 226 + t] = valid ? make_float2(w2r[wi], w2i[wi]) : make_float2(0.f, 0.f);
    }
    __syncthreads();
    int b = tid >> 4, fl = tid & 15;
    const float2* up = U + (size_t)(b * 32 + c) * 1800 + l * 225;
    const float2* wp = Wsh + fl * 226;
    v2f acc = {0.f, 0.f};
#pragma unroll 5
    for (int t = 0; t < 225; ++t) {
        acc += ldv2(up[t]) * ldv2(wp[t]);    // (ur*wr, ui*wi) packed
    }
    float accv = acc.x + acc.y;
    atomicAdd(&feat[b * 64 + fc * 16 + fl], accv);
}

// ---------------- K6: relu(feat) -> conv1d + relu + BN + fc ----------------
__global__ __launch_bounds__(640) void k6_head(const float* __restrict__ feat,
                                               const float* __restrict__ w3,
                                               const float* __restrict__ b3,
                                               const float* __restrict__ gamma,
                                               const float* __restrict__ beta,
                                               const float* __restrict__ fcw,
                                               const float* __restrict__ fcb,
                                               float* __restrict__ out) {
    __shared__ float fL[1024];
    __shared__ float w3L[80];
    __shared__ float b3L[10];
    __shared__ float r3[9120];
    __shared__ float scaleL[10], shiftL[10];
    int tid = threadIdx.x;
    for (int i = tid; i < 1024; i += 640) fL[i] = fmaxf(feat[i], 0.f);
    if (tid < 80) w3L[tid] = w3[tid];
    if (tid >= 80 && tid < 90) b3L[tid - 80] = b3[tid - 80];
    __syncthreads();
    for (int i = tid; i < 9120; i += 640) {
        int ch = i / 912;
        int r = i % 912;
        int b = r / 57, pos = r % 57;
        float acc = b3L[ch];
#pragma unroll
        for (int t = 0; t < 8; ++t) acc += fL[b * 64 + pos + t] * w3L[ch * 8 + t];
        r3[ch * 912 + r] = fmaxf(acc, 0.0f);
    }
    __syncthreads();
    int wave = tid >> 6, lane = tid & 63;
    if (wave < 10) {
        float s = 0.f, s2 = 0.f;
        for (int i = lane; i < 912; i += 64) {
            float v = r3[wave * 912 + i];
            s += v;
            s2 += v * v;
        }
        for (int off = 32; off > 0; off >>= 1) {
            s += __shfl_down(s, off);
            s2 += __shfl_down(s2, off);
        }
        if (lane == 0) {
            float mu = s / 912.0f;
            float var = s2 / 912.0f - mu * mu;
            float sc = gamma[wave] * rsqrtf(var + 1e-5f);
            scaleL[wave] = sc;
            shiftL[wave] = beta[wave] - mu * sc;
        }
    }
    __syncthreads();
    {
        int pair = tid >> 2, sub = tid & 3;
        int b = pair / 10, o = pair % 10;
        float acc = 0.f;
        for (int idx = sub; idx < 570; idx += 4) {
            int ch = idx / 57, pos = idx - ch * 57;
            acc += (r3[ch * 912 + b * 57 + pos] * scaleL[ch] + shiftL[ch])
                   * fcw[o * 570 + idx];
        }
        acc += __shfl_down(acc, 2);
        acc += __shfl_down(acc, 1);
        if (sub == 0) out[b * 10 + o] = acc + fcb[o];
    }
}

extern "C" void kernel_launch(void* const* d_in, const int* in_sizes, int n_in,
                              void* d_out, int out_size, void* d_ws, size_t ws_size,
                              hipStream_t stream) {
    const float* x   = (const float*)d_in[0];
    const float* w1r = (const float*)d_in[1];
    const float* w1i = (const float*)d_in[2];
    const float* w2r = (const float*)d_in[3];
    const float* w2i = (const float*)d_in[4];
    const float* c3w = (const float*)d_in[5];
    const float* c3b = (const float*)d_in[6];
    const float* bng = (const float*)d_in[7];
    const float* bnb = (const float*)d_in[8];
    const float* fcw = (const float*)d_in[9];
    const float* fcb = (const float*)d_in[10];
    float* ws = (float*)d_ws;
    float* out = (float*)d_out;

    hipLaunchKernelGGL(k0a_tables, dim3(1), dim3(256), 0, stream, ws);
    hipLaunchKernelGGL(k0_consts, dim3(1381), dim3(256), 0, stream, ws);
    hipLaunchKernelGGL(k1_xh, dim3(4, 16), dim3(256), 0, stream, x, ws,
                       (float2*)(ws + OFF_XH));
    hipLaunchKernelGGL(k2_planes, dim3(16, 32, 32), dim3(256), 0, stream, w1r, w1i, ws,
                       (float2*)(ws + OFF_XMN));
    hipLaunchKernelGGL(k34_U, dim3(512), dim3(256), 0, stream, ws,
                       (const float2*)(ws + OFF_XMN), (float2*)(ws + OFF_U));
    hipLaunchKernelGGL(k5_feat, dim3(1024), dim3(256), 0, stream, w2r, w2i,
                       (const float2*)(ws + OFF_U), ws + OFF_FEAT);
    hipLaunchKernelGGL(k6_head, dim3(1), dim3(640), 0, stream, ws + OFF_FEAT,
                       c3w, c3b, bng, bnb, fcw, fcb, out);
}

// Round 9
// 271.608 us; speedup vs baseline: 1.0182x; 1.0182x over previous
//
#include <hip/hip_runtime.h>
#include <math.h>

#ifndef M_PI
#define M_PI 3.14159265358979323846
#endif

// ---------------- workspace layout (float offsets) ----------------
#define OFF_TRIG 708              // float2 cs32[32] then cs64[64]  (192 floats)
#define OFF_D1F 900               // [16][64][31]                 31744
#define OFF_D1I 32644             // D1IT: [j=32][mm=16][l=16][nh=32]  262144 (mh>=15 half)
#define OFF_D2F 294788            // D2FT: [j=32][pq=225][l=8]    57600
#define OFF_S2  352388            // [8][15][15]                   1800
#define OFF_XH  354188            // float2 [16][16*31]           15872 floats
#define OFF_XMN 370060            // float2 [16][32][32][113]   3702784 floats (Hermitian half)
#define OFF_U   4072844           // float2 [16*32][8][225]     1843200 floats
#define OFF_FEAT 5916044          // [16][64]                      1024 floats
#define OFF_SENT 5917068          // 2 x u32 sentinel (tables built)

typedef float v2f __attribute__((ext_vector_type(2)));
typedef float v4f __attribute__((ext_vector_type(4)));

static __device__ __forceinline__ int iabs_(int v) { return v < 0 ? -v : v; }

static __device__ __forceinline__ v2f mkv2(float a, float b) {
    v2f r; r.x = a; r.y = b; return r;
}
static __device__ __forceinline__ v2f ldv2(float2 a) { return mkv2(a.x, a.y); }

static __device__ __forceinline__ void ntstore2(float2* p, v2f v) {
    __builtin_nontemporal_store(v, (v2f*)p);
}
static __device__ __forceinline__ v2f ntload2(const float2* p) {
    return __builtin_nontemporal_load((const v2f*)p);
}

static __device__ __forceinline__ double powi_d(double x, int e) {
    double r = 1.0;
    while (e) { if (e & 1) r *= x; x *= x; e >>= 1; }
    return r;
}

// ---------------- K0a: tiny table precompute (1 block) + feat zero ----------------
__global__ __launch_bounds__(256) void k0a_tables(float* __restrict__ ws) {
    int t = threadIdx.x;
    for (int i = t; i < 1024; i += 256) ws[OFF_FEAT + i] = 0.f;   // feat zero (always)
    const unsigned* wsu = (const unsigned*)ws;
    if (wsu[OFF_SENT] == 0x1CEB00DAu && wsu[OFF_SENT + 1] == 0x0DDBA11u) return;

    double* T = (double*)ws;
    __shared__ double lg[64];
    if (t < 64) lg[t] = (t == 0) ? 0.0 : log((double)t);
    __syncthreads();
    if (t == 0) {
        double s = 0.0;
        for (int i = 0; i < 64; ++i) { s += lg[i]; T[i] = s; }   // LF[i]=log(i!)
    }
    if (t < 64) {
        double beta = M_PI * (2.0 * t + 1.0) / 128.0;
        double s = 0.0;
        for (int k = 0; k < 32; ++k) s += sin((2.0 * k + 1.0) * beta) / (2.0 * k + 1.0);
        T[64 + t] = 2.0 / 32.0 * sin(beta) * s;
        T[160 + t] = cos(0.5 * beta);
        T[224 + t] = sin(0.5 * beta);
    }
    if (t >= 64 && t < 96) {
        int j = t - 64;
        double beta = M_PI * (2.0 * j + 1.0) / 64.0;
        double s = 0.0;
        for (int k = 0; k < 16; ++k) s += sin((2.0 * k + 1.0) * beta) / (2.0 * k + 1.0);
        T[128 + j] = 2.0 / 16.0 * sin(beta) * s;
        T[288 + j] = cos(0.5 * beta);
        T[320 + j] = sin(0.5 * beta);
    }
    if (t == 96) {
        T[352] = cos(M_PI / 64.0);
        T[353] = sin(M_PI / 64.0);
    }
    float2* F = (float2*)(ws + OFF_TRIG);
    if (t < 32) {
        double a = 2.0 * M_PI * (double)t / 32.0;
        F[t] = make_float2((float)cos(a), (float)sin(a));
    }
    if (t >= 128 && t < 192) {
        int i = t - 128;
        double a = 2.0 * M_PI * (double)i / 64.0;
        F[32 + i] = make_float2((float)cos(a), (float)sin(a));
    }
}

// ---------------- K0: build Wigner constant tables ----------------
// Divide-free k-loop: reciprocals from a per-block LDS table.
__device__ double wig_fast(int l, int m, int n, double cb, double sb,
                           const double* LF, const double* INV) {
    int kmin = max(0, m - n), kmax = min(l + m, l - n);
    if (kmax < kmin) return 0.0;
    double lc = 0.5 * (LF[l + m] + LF[l - m] + LF[l + n] + LF[l - n])
              - LF[kmin] - LF[l + m - kmin] - LF[l - n - kmin] - LF[n - m + kmin];
    double t = exp(lc) * powi_d(cb, 2 * l + m - n - 2 * kmin)
                       * powi_d(sb, n - m + 2 * kmin);
    if (kmin & 1) t = -t;
    double ratio = (sb * sb) / (cb * cb);
    double s = t;
    for (int k = kmin; k < kmax; ++k) {
        double num = (double)((l + m - k) * (l - n - k));
        t *= -num * INV[k + 1] * INV[n - m + k + 1] * ratio;
        s += t;
    }
    return s;
}

// D1IT stores ONLY the mh>=15 half used by k2: [j][mm=mh-15][l][nh32].
// Total elements: 31744 (D1F) + 262144 (D1IT) + 57600 (D2FT) + 1800 (S2) = 353288.
__global__ __launch_bounds__(256) void k0_consts(float* __restrict__ ws) {
    const unsigned* wsu = (const unsigned*)ws;
    if (wsu[OFF_SENT] == 0x1CEB00DAu && wsu[OFF_SENT + 1] == 0x0DDBA11u) return;

    const double* T = (const double*)ws;
    __shared__ double LF[64];
    __shared__ double INV[64];
    int tid = threadIdx.x;
    if (tid < 64) {
        LF[tid] = T[tid];
        INV[tid] = (tid == 0) ? 0.0 : 1.0 / (double)tid;
    }
    __syncthreads();
    int gid = blockIdx.x * 256 + tid;
    if (gid >= 353288) return;

    if (gid < 31744) {                       // D1F [l][j][mh]
        int mh = gid % 31, j = (gid / 31) % 64, l = gid / (31 * 64);
        int m = mh - 15;
        double v = 0.0;
        if (iabs_(m) <= l)
            v = T[64 + j] * wig_fast(l, m, 0, T[160 + j], T[224 + j], LF, INV);
        ws[OFF_D1F + gid] = (float)v;
    } else if (gid < 293888) {               // D1IT [j][mm][l][nh32], m = mm >= 0
        int r = gid - 31744;
        int nh = r & 31;
        int l  = (r >> 5) & 15;
        int mm = (r >> 9) & 15;
        int j  = r >> 13;
        int n = nh - 15;
        double v = 0.0;
        if (nh < 31 && mm <= l && iabs_(n) <= l)
            v = (2.0 * l + 1.0) * wig_fast(l, mm, n, T[288 + j], T[320 + j], LF, INV);
        ws[OFF_D1I + r] = (float)v;
    } else if (gid < 351488) {               // D2FT [j][pq][l]
        int r = gid - 293888;
        int l = r & 7;
        int pq = (r >> 3) % 225;
        int j = r / 1800;
        int mh = pq / 15, nh = pq % 15;
        int m = mh - 7, n = nh - 7;
        double v = 0.0;
        if (iabs_(m) <= l && iabs_(n) <= l)
            v = T[128 + j] * wig_fast(l, m, n, T[288 + j], T[320 + j], LF, INV);
        ws[OFF_D2F + r] = (float)v;
    } else {                                 // S2 = D2I[:,0,:,:]
        int r = gid - 351488;
        int nh = r % 15, mh = (r / 15) % 15, l = r / 225;
        int m = mh - 7, n = nh - 7;
        double v = 0.0;
        if (iabs_(m) <= l && iabs_(n) <= l)
            v = (2.0 * l + 1.0) * wig_fast(l, m, n, T[352], T[353], LF, INV);
        ws[OFF_S2 + r] = (float)v;
    }
}

// ---------------- K1: x -> xm -> xh (also sets the tables sentinel) ----------------
__global__ __launch_bounds__(256) void k1_xh(const float* __restrict__ x,
                                             float* __restrict__ ws,
                                             float2* __restrict__ xh) {
    __shared__ float  xs[64 * 64];
    __shared__ float2 xm[64 * 8];
    __shared__ float2 cs64[64];
    int c = blockIdx.x, b = blockIdx.y, tid = threadIdx.x;
    if (c == 0 && b == 0 && tid == 0) {      // tables valid from here on
        unsigned* wsu = (unsigned*)ws;
        wsu[OFF_SENT] = 0x1CEB00DAu;
        wsu[OFF_SENT + 1] = 0x0DDBA11u;
    }
    int mh0 = c * 8;
    int cnt = min(8, 31 - mh0);
    for (int i = tid; i < 4096; i += 256) xs[i] = x[b * 4096 + i];
    if (tid < 64) cs64[tid] = ((const float2*)(ws + OFF_TRIG))[32 + tid];
    __syncthreads();
    for (int i = tid; i < 512; i += 256) {
        int j = i >> 3, mi = i & 7;
        if (mi < cnt) {
            int mu = mh0 + mi - 15;
            float re = 0.f, im = 0.f;
            for (int t = 0; t < 64; ++t) {
                float2 w = cs64[(mu * t) & 63];
                float xv = xs[j * 64 + t];
                re += xv * w.x;
                im -= xv * w.y;
            }
            xm[i] = make_float2(re, im);
        }
    }
    __syncthreads();
    const float* D1F = ws + OFF_D1F;
    if (tid < 128) {
        int l = tid >> 3, mi = tid & 7;
        if (mi < cnt) {
            int mh = mh0 + mi;
            float re = 0.f, im = 0.f;
            for (int j = 0; j < 64; ++j) {
                float d = D1F[(l * 64 + j) * 31 + mh];
                float2 v = xm[j * 8 + mi];
                re += d * v.x;
                im += d * v.y;
            }
            xh[b * 496 + l * 31 + mh] = make_float2(re, im);
        }
    }
}

// ------- K2: per-(b,f,j) plane; j-fastest grid (proven write locality).
// Output: only the 113 Hermitian-unique h values per plane, non-temporal,
// fully coalesced (storage index == tid). -------
__global__ __launch_bounds__(256) void k2_planes(const float* __restrict__ w1r,
                                                 const float* __restrict__ w1i,
                                                 const float* __restrict__ ws,
                                                 float2* __restrict__ xmn) {
    __shared__ char ar[13568];
    __shared__ float2 cs2[32];              // (c, s) for e^{2pi i k/32}
    float2* As  = (float2*)ar;              // 496 f2 [0,3968)      (f1 phase)
    float2* Wv  = (float2*)(ar + 4096);     // 512 f2 [4096,8192)   (f1 phase)
    float2* fH  = (float2*)(ar + 8192);     // 16 x 34 f2 [8192,12544) (f1 -> FC)
    float2* FC  = (float2*)ar;              // 4 x 146 f2 [0,4672)  (FC -> t)
    float2* tls = (float2*)(ar + 4672);     // 17 x 34 f2 [4672,9296) (t -> ss)
    float*  ssb = (float*)(ar + 9296);      // 32 x 33 f [9296,13520) (ss -> gg)
    float2* gg  = (float2*)ar;              // 32 x 18 f2 [0,4608)  (gg -> combos)
    float2* Cc  = (float2*)(ar + 4864);     // 4 x 152 f2 [4864,9728) (combos -> h)

    int j = blockIdx.x, f = blockIdx.y, b = blockIdx.z;
    int tid = threadIdx.x;
    const float2* xh = (const float2*)(ws + OFF_XH);

    if (tid < 32) cs2[tid] = ((const float2*)(ws + OFF_TRIG))[tid];
    for (int i = tid; i < 496; i += 256) As[i] = xh[b * 496 + i];
    // V[l,nh] = 0.5*mask*( conj(w1[l,nh]) + (-1)^(nh-15) * w1[l,30-nh] )
    for (int i = tid; i < 512; i += 256) {
        int l = i >> 5, nh = i & 31;
        bool val = (nh < 31 && iabs_(nh - 15) <= l);
        int nhc = val ? nh : 15;
        int base = f * 496 + l * 31;
        float wr1 = w1r[base + nhc], wi1 = w1i[base + nhc];
        float wr2 = w1r[base + 30 - nhc], wi2 = w1i[base + 30 - nhc];
        float s = (nh & 1) ? 1.f : -1.f;
        float vr = 0.5f * (wr1 + s * wr2);
        float vi = 0.5f * (-wi1 + s * wi2);
        Wv[i] = val ? make_float2(vr, vi) : make_float2(0.f, 0.f);
    }
    __syncthreads();
    // ---- fH[mm, nh] = sum_l D1IT[j,mm,l,nh] * A[l,mm+15] * V[l,nh], mm=0..15 ----
    if (tid < 128) {
        int mm = tid >> 3;
        int nh0 = (tid & 7) * 4;
        int mrow = mm + 15;
        v2f a0 = {0.f, 0.f}, a1 = {0.f, 0.f}, a2 = {0.f, 0.f}, a3 = {0.f, 0.f};
        const float* Dbase = ws + OFF_D1I + ((j * 16 + mm) * 16) * 32 + nh0;
        for (int l = mm; l < 16; ++l) {
            float2 a = As[l * 31 + mrow];
            v4f w01 = *(const v4f*)(Wv + l * 32 + nh0);
            v4f w23 = *(const v4f*)(Wv + l * 32 + nh0 + 2);
            v4f d = *(const v4f*)(Dbase + l * 32);
            v2f w, p;
            w = w01.xy; p = a.x * w + a.y * mkv2(-w.y, w.x); a0 += d.x * p;
            w = w01.zw; p = a.x * w + a.y * mkv2(-w.y, w.x); a1 += d.y * p;
            w = w23.xy; p = a.x * w + a.y * mkv2(-w.y, w.x); a2 += d.z * p;
            w = w23.zw; p = a.x * w + a.y * mkv2(-w.y, w.x); a3 += d.w * p;
        }
        float2* fr = fH + mm * 34 + nh0;
        fr[0] = make_float2(a0.x, a0.y);
        fr[1] = make_float2(a1.x, a1.y);
        fr[2] = make_float2(a2.x, a2.y);
        fr[3] = make_float2(a3.x, a3.y);
    }
    __syncthreads();
    // ---- FC_r[mm,n0] = sum_k i^{kr} fH[mm, n0+8k]  (radix-4 input combos) ----
    if (tid < 128) {
        int mm = tid >> 3, n0 = tid & 7;
        const float2* frow = fH + mm * 34 + n0;
        v2f f0 = ldv2(frow[0]), g1 = ldv2(frow[8]), g2 = ldv2(frow[16]), g3 = ldv2(frow[24]);
        v2f E = f0 + g2, F = f0 - g2, G = g1 + g3, H = g1 - g3;
        int base = mm * 9 + n0;
        FC[0 * 146 + base] = make_float2(E.x + G.x, E.y + G.y);   // r=0: E+G
        FC[1 * 146 + base] = make_float2(F.x - H.y, F.y + H.x);   // r=1: F+iH
        FC[2 * 146 + base] = make_float2(E.x - G.x, E.y - G.y);   // r=2: E-G
        FC[3 * 146 + base] = make_float2(F.x + H.y, F.y - H.x);   // r=3: F-iH
    }
    __syncthreads();
    // ---- t[mm, v0+8k'] via S'_r from FC combos ----
    if (tid < 128) {
        int mm = tid >> 3, v0 = tid & 7;
        const float2* fc = FC + (v0 & 3) * 146 + mm * 9;
        v2f S0 = {0.f,0.f}, S1 = {0.f,0.f}, S2 = {0.f,0.f}, S3 = {0.f,0.f};
        v2f w = ldv2(cs2[(17 * v0) & 31]);    // w^{-15 v0}
        v2f st = ldv2(cs2[v0]);               // step w^{v0}
        {
            v2f fv;
            fv = ldv2(fc[0]); S1 += fv.x * w + fv.y * mkv2(-w.y, w.x);
            w = w.x * st + w.y * mkv2(-st.y, st.x);
            fv = ldv2(fc[1]); S2 += fv.x * w + fv.y * mkv2(-w.y, w.x);
            w = w.x * st + w.y * mkv2(-st.y, st.x);
            fv = ldv2(fc[2]); S3 += fv.x * w + fv.y * mkv2(-w.y, w.x);
            w = w.x * st + w.y * mkv2(-st.y, st.x);
            fv = ldv2(fc[3]); S0 += fv.x * w + fv.y * mkv2(-w.y, w.x);
            w = w.x * st + w.y * mkv2(-st.y, st.x);
            fv = ldv2(fc[4]); S1 += fv.x * w + fv.y * mkv2(-w.y, w.x);
            w = w.x * st + w.y * mkv2(-st.y, st.x);
            fv = ldv2(fc[5]); S2 += fv.x * w + fv.y * mkv2(-w.y, w.x);
            w = w.x * st + w.y * mkv2(-st.y, st.x);
            fv = ldv2(fc[6]); S3 += fv.x * w + fv.y * mkv2(-w.y, w.x);
            w = w.x * st + w.y * mkv2(-st.y, st.x);
            fv = ldv2(fc[7]); S0 += fv.x * w + fv.y * mkv2(-w.y, w.x);
        }
        v2f E = S0 + S2, F = S0 - S2, G = S1 + S3, H = S1 - S3;
        v2f A0 = E + G, A2 = E - G;
        v2f iH = mkv2(-H.y, H.x);
        v2f A1 = F + iH, A3 = F - iH;
        float2* trow = tls + mm * 34;
        trow[v0]      = make_float2(A0.x, A0.y);
        trow[v0 + 8]  = make_float2(A1.x, A1.y);
        trow[v0 + 16] = make_float2(A2.x, A2.y);
        trow[v0 + 24] = make_float2(A3.x, A3.y);
    } else if (tid < 162) {
        tls[16 * 34 + (tid - 128)] = make_float2(0.f, 0.f);   // zero row 16
    }
    __syncthreads();
    // ---- ss[u,v] = relu( t[0,v].re + 2 sum_{m=1..15} Re(t[m,v] e^{imu th}) ) ----
    {
        int v = tid & 31, u0 = tid >> 5;
        v2f Z0 = {0.f,0.f}, Z1 = {0.f,0.f}, Z2 = {0.f,0.f}, Z3 = {0.f,0.f};
        v2f y1 = ldv2(cs2[u0]);
        v2f y2 = ldv2(cs2[(2 * u0) & 31]);
        v2f y3 = ldv2(cs2[(3 * u0) & 31]);
        v2f y4 = ldv2(cs2[(4 * u0) & 31]);
        v2f st = y4;                          // step e^{i 4 u0 th}
#pragma unroll
        for (int mb = 1; mb <= 13; mb += 4) {
            float2 tv;
            tv = tls[mb * 34 + v];
            Z1 += tv.x * y1; Z1 += tv.y * mkv2(-y1.y, y1.x);
            tv = tls[(mb + 1) * 34 + v];
            Z2 += tv.x * y2; Z2 += tv.y * mkv2(-y2.y, y2.x);
            tv = tls[(mb + 2) * 34 + v];
            Z3 += tv.x * y3; Z3 += tv.y * mkv2(-y3.y, y3.x);
            tv = tls[(mb + 3) * 34 + v];
            Z0 += tv.x * y4; Z0 += tv.y * mkv2(-y4.y, y4.x);
            y1 = y1.x * st + y1.y * mkv2(-st.y, st.x);
            y2 = y2.x * st + y2.y * mkv2(-st.y, st.x);
            y3 = y3.x * st + y3.y * mkv2(-st.y, st.x);
            y4 = y4.x * st + y4.y * mkv2(-st.y, st.x);
        }
        float E = Z0.x + Z2.x, F = Z0.x - Z2.x;
        float G = Z1.x + Z3.x;
        float Hy = Z1.y - Z3.y;
        float s0 = E + G, s2 = E - G;
        float s1 = F - Hy, s3 = F + Hy;
        float t0x = tls[v].x;
        ssb[u0 * 33 + v]        = fmaxf(t0x + 2.f * s0, 0.f);
        ssb[(u0 + 8) * 33 + v]  = fmaxf(t0x + 2.f * s1, 0.f);
        ssb[(u0 + 16) * 33 + v] = fmaxf(t0x + 2.f * s2, 0.f);
        ssb[(u0 + 24) * 33 + v] = fmaxf(t0x + 2.f * s3, 0.f);
    }
    __syncthreads();
    // ---- gg[u,q'] = sum_v ss[u,v] e^{-i q' v th}, radix-4 over v ----
    {
        int u = tid >> 3, q = tid & 7;
        int qm = q & 3;
        float r1 = (qm == 0) ? 1.f : (qm == 2 ? -1.f : 0.f);
        float r2 = (qm & 1) ? -1.f : 1.f;
        float i1 = (qm == 1) ? -1.f : (qm == 3 ? 1.f : 0.f);
        v2f g = {0.f, 0.f};
        const float* srow = ssb + u * 33;
        v2f w = mkv2(1.f, 0.f);
        v2f st = ldv2(cs2[(32 - q) & 31]);    // step e^{-i q th}
#pragma unroll
        for (int vb = 0; vb < 8; ++vb) {
            float s0 = srow[vb], s1 = srow[vb + 8], s2 = srow[vb + 16], s3 = srow[vb + 24];
            float zre = (s0 + r2 * s2) + r1 * (s1 + s3);
            float zim = i1 * (s1 - s3);
            g += zre * w; g += zim * mkv2(-w.y, w.x);
            w = w.x * st + w.y * mkv2(-st.y, st.x);
        }
        gg[u * 18 + 7 + q] = make_float2(g.x, g.y);
        if (q) gg[u * 18 + 7 - q] = make_float2(g.x, -g.y);
    }
    __syncthreads();
    // ---- C_r[u0,qh] = sum_k i^{-rk} gg[u0+8k, qh]  (radix-4 over u) ----
    if (tid < 120) {
        int u0 = tid / 15, qh = tid % 15;
        v2f g0 = ldv2(gg[u0 * 18 + qh]);
        v2f g1 = ldv2(gg[(u0 + 8) * 18 + qh]);
        v2f g2 = ldv2(gg[(u0 + 16) * 18 + qh]);
        v2f g3 = ldv2(gg[(u0 + 24) * 18 + qh]);
        v2f E = g0 + g2, F = g0 - g2, G = g1 + g3, H = g1 - g3;
        int base = u0 * 19 + qh;
        Cc[0 * 152 + base] = make_float2(E.x + G.x, E.y + G.y);   // r=0: E+G
        Cc[1 * 152 + base] = make_float2(F.x + H.y, F.y - H.x);   // r=1: F-iH
        Cc[2 * 152 + base] = make_float2(E.x - G.x, E.y - G.y);   // r=2: E-G
        Cc[3 * 152 + base] = make_float2(F.x - H.y, F.y + H.x);   // r=3: F+iH
    }
    __syncthreads();
    // ---- h[p,q] = sum_{u0} C_{p&3}[u0,q] e^{-i p u0 th}; store 113 unique only ----
    if (tid < 113) {
        int ph, qh;
        if (tid < 105) { ph = 8 + tid / 15; qh = tid % 15; }
        else           { ph = 7; qh = 7 + (tid - 105); }
        int p = ph - 7;
        const float2* cp = Cc + (p & 3) * 152 + qh;
        v2f h = {0.f, 0.f};
        v2f w = mkv2(1.f, 0.f);
        v2f st = ldv2(cs2[(32 - p) & 31]);    // step e^{-i p th}
#pragma unroll
        for (int u0 = 0; u0 < 8; ++u0) {
            v2f gv = ldv2(cp[u0 * 19]);
            h += gv.x * w + gv.y * mkv2(-w.y, w.x);
            w = w.x * st + w.y * mkv2(-st.y, st.x);
        }
        // storage index == tid (coalesced); mirror reconstructed in k34
        float2* outp = xmn + ((size_t)((b * 32 + f) * 32 + j)) * 113;
        ntstore2(outp + tid, h);
    }
}

// ---------- K34: fused xh2 + U, block per (b,c); Hermitian reconstruction ----------
__global__ __launch_bounds__(256) void k34_U(const float* __restrict__ ws,
                                             const float2* __restrict__ xmn,
                                             float2* __restrict__ U) {
    __shared__ float2 xh2s[1800];
    __shared__ float  S2s[1800];
    int bc = blockIdx.x, tid = threadIdx.x;

    for (int i = tid; i < 1800; i += 256) S2s[i] = ws[OFF_S2 + i];

    v2f a0 = {0.f,0.f}, a1 = {0.f,0.f}, a2 = {0.f,0.f}, a3 = {0.f,0.f};
    v2f a4 = {0.f,0.f}, a5 = {0.f,0.f}, a6 = {0.f,0.f}, a7 = {0.f,0.f};
    if (tid < 225) {
        // Map (ph,qh) -> stored index (113-layout) + conjugation sign
        int ph = tid / 15, qh = tid - ph * 15;
        int sidx; float csign;
        if (ph >= 8)                 { sidx = tid - 120;                csign = 1.f; }
        else if (ph == 7 && qh >= 7) { sidx = tid - 7;                  csign = 1.f; }
        else if (ph == 7)            { sidx = 112 - qh;                 csign = -1.f; }
        else                         { sidx = (6 - ph) * 15 + (14 - qh); csign = -1.f; }

        const float2* xp = xmn + (size_t)bc * 32 * 113;
        const v4f* dw = (const v4f*)(ws + OFF_D2F);
        for (int j = 0; j < 32; ++j) {
            v2f xv = ntload2(xp + j * 113 + sidx);
            xv.y *= csign;
            v4f dA = dw[(j * 225 + tid) * 2];
            v4f dB = dw[(j * 225 + tid) * 2 + 1];
            a0 += dA.x * xv; a1 += dA.y * xv; a2 += dA.z * xv; a3 += dA.w * xv;
            a4 += dB.x * xv; a5 += dB.y * xv; a6 += dB.z * xv; a7 += dB.w * xv;
        }
        xh2s[0 * 225 + tid] = make_float2(a0.x, a0.y);
        xh2s[1 * 225 + tid] = make_float2(a1.x, a1.y);
        xh2s[2 * 225 + tid] = make_float2(a2.x, a2.y);
        xh2s[3 * 225 + tid] = make_float2(a3.x, a3.y);
        xh2s[4 * 225 + tid] = make_float2(a4.x, a4.y);
        xh2s[5 * 225 + tid] = make_float2(a5.x, a5.y);
        xh2s[6 * 225 + tid] = make_float2(a6.x, a6.y);
        xh2s[7 * 225 + tid] = make_float2(a7.x, a7.y);
    }
    __syncthreads();

    for (int idx = tid; idx < 1800; idx += 256) {
        int l = idx / 225;
        int rem = idx - l * 225;
        int n = rem / 15, k = rem - n * 15;
        v2f a = {0.f, 0.f};
        for (int m = 0; m < 15; ++m) {
            float s = S2s[(l * 15 + m) * 15 + n];
            float2 vf = xh2s[l * 225 + m * 15 + k];
            a += s * mkv2(vf.x, vf.y);
        }
        U[(size_t)bc * 1800 + idx] = make_float2(a.x, a.y);
    }
}

// ---------- K5: block per (c,l,fc); W staged in LDS (28.9KB), U streamed ----------
__global__ __launch_bounds__(256) void k5_feat(const float* __restrict__ w2r,
                                               const float* __restrict__ w2i,
                                               const float2* __restrict__ U,
                                               float* __restrict__ feat) {
    __shared__ float2 Wsh[16 * 226];         // 28928 B -> 4-5 blocks/CU
    int bx = blockIdx.x;
    int c = bx >> 5, l = (bx >> 2) & 7, fc = bx & 3;
    int tid = threadIdx.x;

    for (int i = tid; i < 3600; i += 256) {
        int fr = i / 225;
        int f = fc * 16 + fr;
        int t = i - fr * 225;
        int n = t / 15, k = t - n * 15;
        bool valid = (iabs_(n - 7) <= l) && (iabs_(k - 7) <= l);
        int wi = ((c * 64 + f) * 8 + l) * 225 + t;
        Wsh[fr * 226 + t] = valid ? make_float2(w2r[wi], w2i[wi]) : make_float2(0.f, 0.f);
    }
    __syncthreads();
    int b = tid >> 4, fl = tid & 15;
    const float2* up = U + (size_t)(b * 32 + c) * 1800 + l * 225;
    const float2* wp = Wsh + fl * 226;
    v2f acc = {0.f, 0.f};
#pragma unroll 5
    for (int t = 0; t < 225; ++t) {
        acc += ldv2(up[t]) * ldv2(wp[t]);    // (ur*wr, ui*wi) packed
    }
    float accv = acc.x + acc.y;
    atomicAdd(&feat[b * 64 + fc * 16 + fl], accv);
}

// ---------------- K6: relu(feat) -> conv1d + relu + BN + fc ----------------
__global__ __launch_bounds__(640) void k6_head(const float* __restrict__ feat,
                                               const float* __restrict__ w3,
                                               const float* __restrict__ b3,
                                               const float* __restrict__ gamma,
                                               const float* __restrict__ beta,
                                               const float* __restrict__ fcw,
                                               const float* __restrict__ fcb,
                                               float* __restrict__ out) {
    __shared__ float fL[1024];
    __shared__ float w3L[80];
    __shared__ float b3L[10];
    __shared__ float r3[9120];
    __shared__ float scaleL[10], shiftL[10];
    int tid = threadIdx.x;
    for (int i = tid; i < 1024; i += 640) fL[i] = fmaxf(feat[i], 0.f);
    if (tid < 80) w3L[tid] = w3[tid];
    if (tid >= 80 && tid < 90) b3L[tid - 80] = b3[tid - 80];
    __syncthreads();
    for (int i = tid; i < 9120; i += 640) {
        int ch = i / 912;
        int r = i % 912;
        int b = r / 57, pos = r % 57;
        float acc = b3L[ch];
#pragma unroll
        for (int t = 0; t < 8; ++t) acc += fL[b * 64 + pos + t] * w3L[ch * 8 + t];
        r3[ch * 912 + r] = fmaxf(acc, 0.0f);
    }
    __syncthreads();
    int wave = tid >> 6, lane = tid & 63;
    if (wave < 10) {
        float s = 0.f, s2 = 0.f;
        for (int i = lane; i < 912; i += 64) {
            float v = r3[wave * 912 + i];
            s += v;
            s2 += v * v;
        }
        for (int off = 32; off > 0; off >>= 1) {
            s += __shfl_down(s, off);
            s2 += __shfl_down(s2, off);
        }
        if (lane == 0) {
            float mu = s / 912.0f;
            float var = s2 / 912.0f - mu * mu;
            float sc = gamma[wave] * rsqrtf(var + 1e-5f);
            scaleL[wave] = sc;
            shiftL[wave] = beta[wave] - mu * sc;
        }
    }
    __syncthreads();
    {
        int pair = tid >> 2, sub = tid & 3;
        int b = pair / 10, o = pair % 10;
        float acc = 0.f;
        for (int idx = sub; idx < 570; idx += 4) {
            int ch = idx / 57, pos = idx - ch * 57;
            acc += (r3[ch * 912 + b * 57 + pos] * scaleL[ch] + shiftL[ch])
                   * fcw[o * 570 + idx];
        }
        acc += __shfl_down(acc, 2);
        acc += __shfl_down(acc, 1);
        if (sub == 0) out[b * 10 + o] = acc + fcb[o];
    }
}

extern "C" void kernel_launch(void* const* d_in, const int* in_sizes, int n_in,
                              void* d_out, int out_size, void* d_ws, size_t ws_size,
                              hipStream_t stream) {
    const float* x   = (const float*)d_in[0];
    const float* w1r = (const float*)d_in[1];
    const float* w1i = (const float*)d_in[2];
    const float* w2r = (const float*)d_in[3];
    const float* w2i = (const float*)d_in[4];
    const float* c3w = (const float*)d_in[5];
    const float* c3b = (const float*)d_in[6];
    const float* bng = (const float*)d_in[7];
    const float* bnb = (const float*)d_in[8];
    const float* fcw = (const float*)d_in[9];
    const float* fcb = (const float*)d_in[10];
    float* ws = (float*)d_ws;
    float* out = (float*)d_out;

    hipLaunchKernelGGL(k0a_tables, dim3(1), dim3(256), 0, stream, ws);
    hipLaunchKernelGGL(k0_consts, dim3(1381), dim3(256), 0, stream, ws);
    hipLaunchKernelGGL(k1_xh, dim3(4, 16), dim3(256), 0, stream, x, ws,
                       (float2*)(ws + OFF_XH));
    hipLaunchKernelGGL(k2_planes, dim3(32, 32, 16), dim3(256), 0, stream, w1r, w1i, ws,
                       (float2*)(ws + OFF_XMN));
    hipLaunchKernelGGL(k34_U, dim3(512), dim3(256), 0, stream, ws,
                       (const float2*)(ws + OFF_XMN), (float2*)(ws + OFF_U));
    hipLaunchKernelGGL(k5_feat, dim3(1024), dim3(256), 0, stream, w2r, w2i,
                       (const float2*)(ws + OFF_U), ws + OFF_FEAT);
    hipLaunchKernelGGL(k6_head, dim3(1), dim3(640), 0, stream, ws + OFF_FEAT,
                       c3w, c3b, bng, bnb, fcw, fcb, out);
}

// Round 10
// 268.920 us; speedup vs baseline: 1.0284x; 1.0100x over previous
//
#include <hip/hip_runtime.h>
#include <math.h>

#ifndef M_PI
#define M_PI 3.14159265358979323846
#endif

// ---------------- workspace layout (float offsets) ----------------
#define OFF_TRIG 708              // float2 cs32[32] then cs64[64]  (192 floats)
#define OFF_D1F 900               // [16][64][31]                 31744
#define OFF_D1I 32644             // D1IT: [j=32][mm=16][l=16][nh=32]  262144 (mh>=15 half)
#define OFF_D2F 294788            // D2FT: [j=32][pq=225][l=8]    57600
#define OFF_S2  352388            // [8][15][15]                   1800
#define OFF_XH  354188            // float2 [16][16*31]           15872 floats
#define OFF_XMN 370060            // float2 [16][32][32][113]   3702784 floats (Hermitian half)
#define OFF_U   4072844           // float2 [16*32][8][225]     1843200 floats
#define OFF_FEAT 5916044          // [16][64]                      1024 floats
#define OFF_SENT 5917068          // 2 x u32 sentinel (tables built)

typedef float v2f __attribute__((ext_vector_type(2)));
typedef float v4f __attribute__((ext_vector_type(4)));

static __device__ __forceinline__ int iabs_(int v) { return v < 0 ? -v : v; }

static __device__ __forceinline__ v2f mkv2(float a, float b) {
    v2f r; r.x = a; r.y = b; return r;
}
static __device__ __forceinline__ v2f ldv2(float2 a) { return mkv2(a.x, a.y); }

static __device__ __forceinline__ void ntstore2(float2* p, v2f v) {
    __builtin_nontemporal_store(v, (v2f*)p);
}
static __device__ __forceinline__ v2f ntload2(const float2* p) {
    return __builtin_nontemporal_load((const v2f*)p);
}

static __device__ __forceinline__ double powi_d(double x, int e) {
    double r = 1.0;
    while (e) { if (e & 1) r *= x; x *= x; e >>= 1; }
    return r;
}

// ---------------- K0a: tiny table precompute (1 block) + feat zero ----------------
__global__ __launch_bounds__(256) void k0a_tables(float* __restrict__ ws) {
    int t = threadIdx.x;
    for (int i = t; i < 1024; i += 256) ws[OFF_FEAT + i] = 0.f;   // feat zero (always)
    const unsigned* wsu = (const unsigned*)ws;
    if (wsu[OFF_SENT] == 0x1CEB00DAu && wsu[OFF_SENT + 1] == 0x0DDBA11u) return;

    double* T = (double*)ws;
    __shared__ double lg[64];
    if (t < 64) lg[t] = (t == 0) ? 0.0 : log((double)t);
    __syncthreads();
    if (t == 0) {
        double s = 0.0;
        for (int i = 0; i < 64; ++i) { s += lg[i]; T[i] = s; }   // LF[i]=log(i!)
    }
    if (t < 64) {
        double beta = M_PI * (2.0 * t + 1.0) / 128.0;
        double s = 0.0;
        for (int k = 0; k < 32; ++k) s += sin((2.0 * k + 1.0) * beta) / (2.0 * k + 1.0);
        T[64 + t] = 2.0 / 32.0 * sin(beta) * s;
        T[160 + t] = cos(0.5 * beta);
        T[224 + t] = sin(0.5 * beta);
    }
    if (t >= 64 && t < 96) {
        int j = t - 64;
        double beta = M_PI * (2.0 * j + 1.0) / 64.0;
        double s = 0.0;
        for (int k = 0; k < 16; ++k) s += sin((2.0 * k + 1.0) * beta) / (2.0 * k + 1.0);
        T[128 + j] = 2.0 / 16.0 * sin(beta) * s;
        T[288 + j] = cos(0.5 * beta);
        T[320 + j] = sin(0.5 * beta);
    }
    if (t == 96) {
        T[352] = cos(M_PI / 64.0);
        T[353] = sin(M_PI / 64.0);
    }
    float2* F = (float2*)(ws + OFF_TRIG);
    if (t < 32) {
        double a = 2.0 * M_PI * (double)t / 32.0;
        F[t] = make_float2((float)cos(a), (float)sin(a));
    }
    if (t >= 128 && t < 192) {
        int i = t - 128;
        double a = 2.0 * M_PI * (double)i / 64.0;
        F[32 + i] = make_float2((float)cos(a), (float)sin(a));
    }
}

// ---------------- K0: build Wigner constant tables ----------------
// Divide-free k-loop: reciprocals from a per-block LDS table.
__device__ double wig_fast(int l, int m, int n, double cb, double sb,
                           const double* LF, const double* INV) {
    int kmin = max(0, m - n), kmax = min(l + m, l - n);
    if (kmax < kmin) return 0.0;
    double lc = 0.5 * (LF[l + m] + LF[l - m] + LF[l + n] + LF[l - n])
              - LF[kmin] - LF[l + m - kmin] - LF[l - n - kmin] - LF[n - m + kmin];
    double t = exp(lc) * powi_d(cb, 2 * l + m - n - 2 * kmin)
                       * powi_d(sb, n - m + 2 * kmin);
    if (kmin & 1) t = -t;
    double ratio = (sb * sb) / (cb * cb);
    double s = t;
    for (int k = kmin; k < kmax; ++k) {
        double num = (double)((l + m - k) * (l - n - k));
        t *= -num * INV[k + 1] * INV[n - m + k + 1] * ratio;
        s += t;
    }
    return s;
}

// D1IT stores ONLY the mh>=15 half used by k2: [j][mm=mh-15][l][nh32].
// Total elements: 31744 (D1F) + 262144 (D1IT) + 57600 (D2FT) + 1800 (S2) = 353288.
__global__ __launch_bounds__(256) void k0_consts(float* __restrict__ ws) {
    const unsigned* wsu = (const unsigned*)ws;
    if (wsu[OFF_SENT] == 0x1CEB00DAu && wsu[OFF_SENT + 1] == 0x0DDBA11u) return;

    const double* T = (const double*)ws;
    __shared__ double LF[64];
    __shared__ double INV[64];
    int tid = threadIdx.x;
    if (tid < 64) {
        LF[tid] = T[tid];
        INV[tid] = (tid == 0) ? 0.0 : 1.0 / (double)tid;
    }
    __syncthreads();
    int gid = blockIdx.x * 256 + tid;
    if (gid >= 353288) return;

    if (gid < 31744) {                       // D1F [l][j][mh]
        int mh = gid % 31, j = (gid / 31) % 64, l = gid / (31 * 64);
        int m = mh - 15;
        double v = 0.0;
        if (iabs_(m) <= l)
            v = T[64 + j] * wig_fast(l, m, 0, T[160 + j], T[224 + j], LF, INV);
        ws[OFF_D1F + gid] = (float)v;
    } else if (gid < 293888) {               // D1IT [j][mm][l][nh32], m = mm >= 0
        int r = gid - 31744;
        int nh = r & 31;
        int l  = (r >> 5) & 15;
        int mm = (r >> 9) & 15;
        int j  = r >> 13;
        int n = nh - 15;
        double v = 0.0;
        if (nh < 31 && mm <= l && iabs_(n) <= l)
            v = (2.0 * l + 1.0) * wig_fast(l, mm, n, T[288 + j], T[320 + j], LF, INV);
        ws[OFF_D1I + r] = (float)v;
    } else if (gid < 351488) {               // D2FT [j][pq][l]
        int r = gid - 293888;
        int l = r & 7;
        int pq = (r >> 3) % 225;
        int j = r / 1800;
        int mh = pq / 15, nh = pq % 15;
        int m = mh - 7, n = nh - 7;
        double v = 0.0;
        if (iabs_(m) <= l && iabs_(n) <= l)
            v = T[128 + j] * wig_fast(l, m, n, T[288 + j], T[320 + j], LF, INV);
        ws[OFF_D2F + r] = (float)v;
    } else {                                 // S2 = D2I[:,0,:,:]
        int r = gid - 351488;
        int nh = r % 15, mh = (r / 15) % 15, l = r / 225;
        int m = mh - 7, n = nh - 7;
        double v = 0.0;
        if (iabs_(m) <= l && iabs_(n) <= l)
            v = (2.0 * l + 1.0) * wig_fast(l, m, n, T[352], T[353], LF, INV);
        ws[OFF_S2 + r] = (float)v;
    }
}

// ---------------- K1: x -> xm -> xh (also sets the tables sentinel) ----------------
__global__ __launch_bounds__(256) void k1_xh(const float* __restrict__ x,
                                             float* __restrict__ ws,
                                             float2* __restrict__ xh) {
    __shared__ float  xs[64 * 64];
    __shared__ float2 xm[64 * 8];
    __shared__ float2 cs64[64];
    int c = blockIdx.x, b = blockIdx.y, tid = threadIdx.x;
    if (c == 0 && b == 0 && tid == 0) {      // tables valid from here on
        unsigned* wsu = (unsigned*)ws;
        wsu[OFF_SENT] = 0x1CEB00DAu;
        wsu[OFF_SENT + 1] = 0x0DDBA11u;
    }
    int mh0 = c * 8;
    int cnt = min(8, 31 - mh0);
    for (int i = tid; i < 4096; i += 256) xs[i] = x[b * 4096 + i];
    if (tid < 64) cs64[tid] = ((const float2*)(ws + OFF_TRIG))[32 + tid];
    __syncthreads();
    for (int i = tid; i < 512; i += 256) {
        int j = i >> 3, mi = i & 7;
        if (mi < cnt) {
            int mu = mh0 + mi - 15;
            float re = 0.f, im = 0.f;
            for (int t = 0; t < 64; ++t) {
                float2 w = cs64[(mu * t) & 63];
                float xv = xs[j * 64 + t];
                re += xv * w.x;
                im -= xv * w.y;
            }
            xm[i] = make_float2(re, im);
        }
    }
    __syncthreads();
    const float* D1F = ws + OFF_D1F;
    if (tid < 128) {
        int l = tid >> 3, mi = tid & 7;
        if (mi < cnt) {
            int mh = mh0 + mi;
            float re = 0.f, im = 0.f;
            for (int j = 0; j < 64; ++j) {
                float d = D1F[(l * 64 + j) * 31 + mh];
                float2 v = xm[j * 8 + mi];
                re += d * v.x;
                im += d * v.y;
            }
            xh[b * 496 + l * 31 + mh] = make_float2(re, im);
        }
    }
}

// ------- K2: per-(b,f,j) plane; j-fastest grid; Hermitian-half output.
// This round: ph1 at full 256-thread width (2 cols/thread), and all twiddle
// register-chains replaced by direct cs2 table reads (exact, off-VALU). -------
__global__ __launch_bounds__(256) void k2_planes(const float* __restrict__ w1r,
                                                 const float* __restrict__ w1i,
                                                 const float* __restrict__ ws,
                                                 float2* __restrict__ xmn) {
    __shared__ char ar[13568];
    __shared__ float2 cs2[32];              // (c, s) for e^{2pi i k/32}
    float2* As  = (float2*)ar;              // 496 f2 [0,3968)      (f1 phase)
    float2* Wv  = (float2*)(ar + 4096);     // 512 f2 [4096,8192)   (f1 phase)
    float2* fH  = (float2*)(ar + 8192);     // 16 x 34 f2 [8192,12544) (f1 -> FC)
    float2* FC  = (float2*)ar;              // 4 x 146 f2 [0,4672)  (FC -> t)
    float2* tls = (float2*)(ar + 4672);     // 17 x 34 f2 [4672,9296) (t -> ss)
    float*  ssb = (float*)(ar + 9296);      // 32 x 33 f [9296,13520) (ss -> gg)
    float2* gg  = (float2*)ar;              // 32 x 18 f2 [0,4608)  (gg -> combos)
    float2* Cc  = (float2*)(ar + 4864);     // 4 x 152 f2 [4864,9728) (combos -> h)

    int j = blockIdx.x, f = blockIdx.y, b = blockIdx.z;
    int tid = threadIdx.x;
    const float2* xh = (const float2*)(ws + OFF_XH);

    if (tid < 32) cs2[tid] = ((const float2*)(ws + OFF_TRIG))[tid];
    for (int i = tid; i < 496; i += 256) As[i] = xh[b * 496 + i];
    // V[l,nh] = 0.5*mask*( conj(w1[l,nh]) + (-1)^(nh-15) * w1[l,30-nh] )
    for (int i = tid; i < 512; i += 256) {
        int l = i >> 5, nh = i & 31;
        bool val = (nh < 31 && iabs_(nh - 15) <= l);
        int nhc = val ? nh : 15;
        int base = f * 496 + l * 31;
        float wr1 = w1r[base + nhc], wi1 = w1i[base + nhc];
        float wr2 = w1r[base + 30 - nhc], wi2 = w1i[base + 30 - nhc];
        float s = (nh & 1) ? 1.f : -1.f;
        float vr = 0.5f * (wr1 + s * wr2);
        float vi = 0.5f * (-wi1 + s * wi2);
        Wv[i] = val ? make_float2(vr, vi) : make_float2(0.f, 0.f);
    }
    __syncthreads();
    // ---- ph1 (FULL WIDTH): fH[mm,nh] = sum_l D1IT[j,mm,l,nh]*A[l,mm+15]*V[l,nh]
    //      16 rows x 16 threads x 2 cols ----
    {
        int mm = tid >> 4, cp = tid & 15;
        int nh0 = cp * 2;
        int mrow = mm + 15;
        v2f a0 = {0.f, 0.f}, a1 = {0.f, 0.f};
        const float* Dbase = ws + OFF_D1I + ((j * 16 + mm) * 16) * 32 + nh0;
        for (int l = mm; l < 16; ++l) {
            float2 a = As[l * 31 + mrow];
            v4f w01 = *(const v4f*)(Wv + l * 32 + nh0);
            float2 d = *(const float2*)(Dbase + l * 32);
            v2f w, p;
            w = w01.xy; p = a.x * w + a.y * mkv2(-w.y, w.x); a0 += d.x * p;
            w = w01.zw; p = a.x * w + a.y * mkv2(-w.y, w.x); a1 += d.y * p;
        }
        v4f out; out.x = a0.x; out.y = a0.y; out.z = a1.x; out.w = a1.y;
        *(v4f*)(fH + mm * 34 + nh0) = out;
    }
    __syncthreads();
    // ---- FC_r[mm,n0] = sum_k i^{kr} fH[mm, n0+8k]  (radix-4 input combos) ----
    if (tid < 128) {
        int mm = tid >> 3, n0 = tid & 7;
        const float2* frow = fH + mm * 34 + n0;
        v2f f0 = ldv2(frow[0]), g1 = ldv2(frow[8]), g2 = ldv2(frow[16]), g3 = ldv2(frow[24]);
        v2f E = f0 + g2, F = f0 - g2, G = g1 + g3, H = g1 - g3;
        int base = mm * 9 + n0;
        FC[0 * 146 + base] = make_float2(E.x + G.x, E.y + G.y);   // r=0: E+G
        FC[1 * 146 + base] = make_float2(F.x - H.y, F.y + H.x);   // r=1: F+iH
        FC[2 * 146 + base] = make_float2(E.x - G.x, E.y - G.y);   // r=2: E-G
        FC[3 * 146 + base] = make_float2(F.x + H.y, F.y - H.x);   // r=3: F-iH
    }
    __syncthreads();
    // ---- t[mm, v0+8k'] via S'_r from FC combos; twiddles from cs2 table ----
    if (tid < 128) {
        int mm = tid >> 3, v0 = tid & 7;
        const float2* fc = FC + (v0 & 3) * 146 + mm * 9;
        v2f S0 = {0.f,0.f}, S1 = {0.f,0.f}, S2 = {0.f,0.f}, S3 = {0.f,0.f};
        int ci = 17 * v0;
        v2f fv, w;
        fv = ldv2(fc[0]); w = ldv2(cs2[ci & 31]); ci += v0;
        S1 += fv.x * w + fv.y * mkv2(-w.y, w.x);
        fv = ldv2(fc[1]); w = ldv2(cs2[ci & 31]); ci += v0;
        S2 += fv.x * w + fv.y * mkv2(-w.y, w.x);
        fv = ldv2(fc[2]); w = ldv2(cs2[ci & 31]); ci += v0;
        S3 += fv.x * w + fv.y * mkv2(-w.y, w.x);
        fv = ldv2(fc[3]); w = ldv2(cs2[ci & 31]); ci += v0;
        S0 += fv.x * w + fv.y * mkv2(-w.y, w.x);
        fv = ldv2(fc[4]); w = ldv2(cs2[ci & 31]); ci += v0;
        S1 += fv.x * w + fv.y * mkv2(-w.y, w.x);
        fv = ldv2(fc[5]); w = ldv2(cs2[ci & 31]); ci += v0;
        S2 += fv.x * w + fv.y * mkv2(-w.y, w.x);
        fv = ldv2(fc[6]); w = ldv2(cs2[ci & 31]); ci += v0;
        S3 += fv.x * w + fv.y * mkv2(-w.y, w.x);
        fv = ldv2(fc[7]); w = ldv2(cs2[ci & 31]);
        S0 += fv.x * w + fv.y * mkv2(-w.y, w.x);
        v2f E = S0 + S2, F = S0 - S2, G = S1 + S3, H = S1 - S3;
        v2f A0 = E + G, A2 = E - G;
        v2f iH = mkv2(-H.y, H.x);
        v2f A1 = F + iH, A3 = F - iH;
        float2* trow = tls + mm * 34;
        trow[v0]      = make_float2(A0.x, A0.y);
        trow[v0 + 8]  = make_float2(A1.x, A1.y);
        trow[v0 + 16] = make_float2(A2.x, A2.y);
        trow[v0 + 24] = make_float2(A3.x, A3.y);
    } else if (tid < 162) {
        tls[16 * 34 + (tid - 128)] = make_float2(0.f, 0.f);   // zero row 16
    }
    __syncthreads();
    // ---- ss[u,v] = relu( t[0,v].re + 2 sum_{m=1..15} Re(t[m,v] e^{imu th}) )
    //      twiddles cs2[(m*u0)&31] (broadcast: u0 has 2 values per wave) ----
    {
        int v = tid & 31, u0 = tid >> 5;
        v2f Z0 = {0.f,0.f}, Z1 = {0.f,0.f}, Z2 = {0.f,0.f}, Z3 = {0.f,0.f};
        int c1 = u0, c2 = 2 * u0, c3 = 3 * u0, c4 = 4 * u0;
        int s4 = 4 * u0;
#pragma unroll
        for (int mb = 1; mb <= 13; mb += 4) {
            float2 tv; v2f y;
            tv = tls[mb * 34 + v];       y = ldv2(cs2[c1 & 31]);
            Z1 += tv.x * y + tv.y * mkv2(-y.y, y.x);
            tv = tls[(mb + 1) * 34 + v]; y = ldv2(cs2[c2 & 31]);
            Z2 += tv.x * y + tv.y * mkv2(-y.y, y.x);
            tv = tls[(mb + 2) * 34 + v]; y = ldv2(cs2[c3 & 31]);
            Z3 += tv.x * y + tv.y * mkv2(-y.y, y.x);
            tv = tls[(mb + 3) * 34 + v]; y = ldv2(cs2[c4 & 31]);
            Z0 += tv.x * y + tv.y * mkv2(-y.y, y.x);
            c1 += s4; c2 += s4; c3 += s4; c4 += s4;
        }
        float E = Z0.x + Z2.x, F = Z0.x - Z2.x;
        float G = Z1.x + Z3.x;
        float Hy = Z1.y - Z3.y;
        float s0 = E + G, s2 = E - G;
        float s1 = F - Hy, s3 = F + Hy;
        float t0x = tls[v].x;
        ssb[u0 * 33 + v]        = fmaxf(t0x + 2.f * s0, 0.f);
        ssb[(u0 + 8) * 33 + v]  = fmaxf(t0x + 2.f * s1, 0.f);
        ssb[(u0 + 16) * 33 + v] = fmaxf(t0x + 2.f * s2, 0.f);
        ssb[(u0 + 24) * 33 + v] = fmaxf(t0x + 2.f * s3, 0.f);
    }
    __syncthreads();
    // ---- gg[u,q'] = sum_v ss[u,v] e^{-i q' v th}; twiddles from table ----
    {
        int u = tid >> 3, q = tid & 7;
        int qm = q & 3;
        float r1 = (qm == 0) ? 1.f : (qm == 2 ? -1.f : 0.f);
        float r2 = (qm & 1) ? -1.f : 1.f;
        float i1 = (qm == 1) ? -1.f : (qm == 3 ? 1.f : 0.f);
        v2f g = {0.f, 0.f};
        const float* srow = ssb + u * 33;
        int ci = 0;
#pragma unroll
        for (int vb = 0; vb < 8; ++vb) {
            float s0 = srow[vb], s1 = srow[vb + 8], s2 = srow[vb + 16], s3 = srow[vb + 24];
            float zre = (s0 + r2 * s2) + r1 * (s1 + s3);
            float zim = i1 * (s1 - s3);
            v2f w = ldv2(cs2[ci & 31]);
            g += zre * w + zim * mkv2(-w.y, w.x);
            ci -= q;
        }
        gg[u * 18 + 7 + q] = make_float2(g.x, g.y);
        if (q) gg[u * 18 + 7 - q] = make_float2(g.x, -g.y);
    }
    __syncthreads();
    // ---- C_r[u0,qh] = sum_k i^{-rk} gg[u0+8k, qh]  (radix-4 over u) ----
    if (tid < 120) {
        int u0 = tid / 15, qh = tid % 15;
        v2f g0 = ldv2(gg[u0 * 18 + qh]);
        v2f g1 = ldv2(gg[(u0 + 8) * 18 + qh]);
        v2f g2 = ldv2(gg[(u0 + 16) * 18 + qh]);
        v2f g3 = ldv2(gg[(u0 + 24) * 18 + qh]);
        v2f E = g0 + g2, F = g0 - g2, G = g1 + g3, H = g1 - g3;
        int base = u0 * 19 + qh;
        Cc[0 * 152 + base] = make_float2(E.x + G.x, E.y + G.y);   // r=0: E+G
        Cc[1 * 152 + base] = make_float2(F.x + H.y, F.y - H.x);   // r=1: F-iH
        Cc[2 * 152 + base] = make_float2(E.x - G.x, E.y - G.y);   // r=2: E-G
        Cc[3 * 152 + base] = make_float2(F.x - H.y, F.y + H.x);   // r=3: F+iH
    }
    __syncthreads();
    // ---- h[p,q] = sum_{u0} C_{p&3}[u0,q] e^{-i p u0 th}; store 113 unique ----
    if (tid < 113) {
        int ph, qh;
        if (tid < 105) { ph = 8 + tid / 15; qh = tid % 15; }
        else           { ph = 7; qh = 7 + (tid - 105); }
        int p = ph - 7;
        const float2* cp = Cc + (p & 3) * 152 + qh;
        v2f h = {0.f, 0.f};
        int ci = 0;
#pragma unroll
        for (int u0 = 0; u0 < 8; ++u0) {
            v2f gv = ldv2(cp[u0 * 19]);
            v2f w = ldv2(cs2[ci & 31]);
            h += gv.x * w + gv.y * mkv2(-w.y, w.x);
            ci -= p;
        }
        // storage index == tid (coalesced); mirror reconstructed in k34
        float2* outp = xmn + ((size_t)((b * 32 + f) * 32 + j)) * 113;
        ntstore2(outp + tid, h);
    }
}

// ---------- K34: fused xh2 + U, block per (b,c); Hermitian reconstruction ----------
__global__ __launch_bounds__(256) void k34_U(const float* __restrict__ ws,
                                             const float2* __restrict__ xmn,
                                             float2* __restrict__ U) {
    __shared__ float2 xh2s[1800];
    __shared__ float  S2s[1800];
    int bc = blockIdx.x, tid = threadIdx.x;

    for (int i = tid; i < 1800; i += 256) S2s[i] = ws[OFF_S2 + i];

    v2f a0 = {0.f,0.f}, a1 = {0.f,0.f}, a2 = {0.f,0.f}, a3 = {0.f,0.f};
    v2f a4 = {0.f,0.f}, a5 = {0.f,0.f}, a6 = {0.f,0.f}, a7 = {0.f,0.f};
    if (tid < 225) {
        // Map (ph,qh) -> stored index (113-layout) + conjugation sign
        int ph = tid / 15, qh = tid - ph * 15;
        int sidx; float csign;
        if (ph >= 8)                 { sidx = tid - 120;                csign = 1.f; }
        else if (ph == 7 && qh >= 7) { sidx = tid - 7;                  csign = 1.f; }
        else if (ph == 7)            { sidx = 112 - qh;                 csign = -1.f; }
        else                         { sidx = (6 - ph) * 15 + (14 - qh); csign = -1.f; }

        const float2* xp = xmn + (size_t)bc * 32 * 113;
        const v4f* dw = (const v4f*)(ws + OFF_D2F);
        for (int j = 0; j < 32; ++j) {
            v2f xv = ntload2(xp + j * 113 + sidx);
            xv.y *= csign;
            v4f dA = dw[(j * 225 + tid) * 2];
            v4f dB = dw[(j * 225 + tid) * 2 + 1];
            a0 += dA.x * xv; a1 += dA.y * xv; a2 += dA.z * xv; a3 += dA.w * xv;
            a4 += dB.x * xv; a5 += dB.y * xv; a6 += dB.z * xv; a7 += dB.w * xv;
        }
        xh2s[0 * 225 + tid] = make_float2(a0.x, a0.y);
        xh2s[1 * 225 + tid] = make_float2(a1.x, a1.y);
        xh2s[2 * 225 + tid] = make_float2(a2.x, a2.y);
        xh2s[3 * 225 + tid] = make_float2(a3.x, a3.y);
        xh2s[4 * 225 + tid] = make_float2(a4.x, a4.y);
        xh2s[5 * 225 + tid] = make_float2(a5.x, a5.y);
        xh2s[6 * 225 + tid] = make_float2(a6.x, a6.y);
        xh2s[7 * 225 + tid] = make_float2(a7.x, a7.y);
    }
    __syncthreads();

    for (int idx = tid; idx < 1800; idx += 256) {
        int l = idx / 225;
        int rem = idx - l * 225;
        int n = rem / 15, k = rem - n * 15;
        v2f a = {0.f, 0.f};
        for (int m = 0; m < 15; ++m) {
            float s = S2s[(l * 15 + m) * 15 + n];
            float2 vf = xh2s[l * 225 + m * 15 + k];
            a += s * mkv2(vf.x, vf.y);
        }
        U[(size_t)bc * 1800 + idx] = make_float2(a.x, a.y);
    }
}

// ---------- K5: block per (c,l,fc); W staged in LDS (28.9KB), U streamed ----------
__global__ __launch_bounds__(256) void k5_feat(const float* __restrict__ w2r,
                                               const float* __restrict__ w2i,
                                               const float2* __restrict__ U,
                                               float* __restrict__ feat) {
    __shared__ float2 Wsh[16 * 226];         // 28928 B -> 4-5 blocks/CU
    int bx = blockIdx.x;
    int c = bx >> 5, l = (bx >> 2) & 7, fc = bx & 3;
    int tid = threadIdx.x;

    for (int i = tid; i < 3600; i += 256) {
        int fr = i / 225;
        int f = fc * 16 + fr;
        int t = i - fr * 225;
        int n = t / 15, k = t - n * 15;
        bool valid = (iabs_(n - 7) <= l) && (iabs_(k - 7) <= l);
        int wi = ((c * 64 + f) * 8 + l) * 225 + t;
        Wsh[fr * 226 + t] = valid ? make_float2(w2r[wi], w2i[wi]) : make_float2(0.f, 0.f);
    }
    __syncthreads();
    int b = tid >> 4, fl = tid & 15;
    const float2* up = U + (size_t)(b * 32 + c) * 1800 + l * 225;
    const float2* wp = Wsh + fl * 226;
    v2f acc = {0.f, 0.f};
#pragma unroll 5
    for (int t = 0; t < 225; ++t) {
        acc += ldv2(up[t]) * ldv2(wp[t]);    // (ur*wr, ui*wi) packed
    }
    float accv = acc.x + acc.y;
    atomicAdd(&feat[b * 64 + fc * 16 + fl], accv);
}

// ---------------- K6: relu(feat) -> conv1d + relu + BN + fc ----------------
__global__ __launch_bounds__(640) void k6_head(const float* __restrict__ feat,
                                               const float* __restrict__ w3,
                                               const float* __restrict__ b3,
                                               const float* __restrict__ gamma,
                                               const float* __restrict__ beta,
                                               const float* __restrict__ fcw,
                                               const float* __restrict__ fcb,
                                               float* __restrict__ out) {
    __shared__ float fL[1024];
    __shared__ float w3L[80];
    __shared__ float b3L[10];
    __shared__ float r3[9120];
    __shared__ float scaleL[10], shiftL[10];
    int tid = threadIdx.x;
    for (int i = tid; i < 1024; i += 640) fL[i] = fmaxf(feat[i], 0.f);
    if (tid < 80) w3L[tid] = w3[tid];
    if (tid >= 80 && tid < 90) b3L[tid - 80] = b3[tid - 80];
    __syncthreads();
    for (int i = tid; i < 9120; i += 640) {
        int ch = i / 912;
        int r = i % 912;
        int b = r / 57, pos = r % 57;
        float acc = b3L[ch];
#pragma unroll
        for (int t = 0; t < 8; ++t) acc += fL[b * 64 + pos + t] * w3L[ch * 8 + t];
        r3[ch * 912 + r] = fmaxf(acc, 0.0f);
    }
    __syncthreads();
    int wave = tid >> 6, lane = tid & 63;
    if (wave < 10) {
        float s = 0.f, s2 = 0.f;
        for (int i = lane; i < 912; i += 64) {
            float v = r3[wave * 912 + i];
            s += v;
            s2 += v * v;
        }
        for (int off = 32; off > 0; off >>= 1) {
            s += __shfl_down(s, off);
            s2 += __shfl_down(s2, off);
        }
        if (lane == 0) {
            float mu = s / 912.0f;
            float var = s2 / 912.0f - mu * mu;
            float sc = gamma[wave] * rsqrtf(var + 1e-5f);
            scaleL[wave] = sc;
            shiftL[wave] = beta[wave] - mu * sc;
        }
    }
    __syncthreads();
    {
        int pair = tid >> 2, sub = tid & 3;
        int b = pair / 10, o = pair % 10;
        float acc = 0.f;
        for (int idx = sub; idx < 570; idx += 4) {
            int ch = idx / 57, pos = idx - ch * 57;
            acc += (r3[ch * 912 + b * 57 + pos] * scaleL[ch] + shiftL[ch])
                   * fcw[o * 570 + idx];
        }
        acc += __shfl_down(acc, 2);
        acc += __shfl_down(acc, 1);
        if (sub == 0) out[b * 10 + o] = acc + fcb[o];
    }
}

extern "C" void kernel_launch(void* const* d_in, const int* in_sizes, int n_in,
                              void* d_out, int out_size, void* d_ws, size_t ws_size,
                              hipStream_t stream) {
    const float* x   = (const float*)d_in[0];
    const float* w1r = (const float*)d_in[1];
    const float* w1i = (const float*)d_in[2];
    const float* w2r = (const float*)d_in[3];
    const float* w2i = (const float*)d_in[4];
    const float* c3w = (const float*)d_in[5];
    const float* c3b = (const float*)d_in[6];
    const float* bng = (const float*)d_in[7];
    const float* bnb = (const float*)d_in[8];
    const float* fcw = (const float*)d_in[9];
    const float* fcb = (const float*)d_in[10];
    float* ws = (float*)d_ws;
    float* out = (float*)d_out;

    hipLaunchKernelGGL(k0a_tables, dim3(1), dim3(256), 0, stream, ws);
    hipLaunchKernelGGL(k0_consts, dim3(1381), dim3(256), 0, stream, ws);
    hipLaunchKernelGGL(k1_xh, dim3(4, 16), dim3(256), 0, stream, x, ws,
                       (float2*)(ws + OFF_XH));
    hipLaunchKernelGGL(k2_planes, dim3(32, 32, 16), dim3(256), 0, stream, w1r, w1i, ws,
                       (float2*)(ws + OFF_XMN));
    hipLaunchKernelGGL(k34_U, dim3(512), dim3(256), 0, stream, ws,
                       (const float2*)(ws + OFF_XMN), (float2*)(ws + OFF_U));
    hipLaunchKernelGGL(k5_feat, dim3(1024), dim3(256), 0, stream, w2r, w2i,
                       (const float2*)(ws + OFF_U), ws + OFF_FEAT);
    hipLaunchKernelGGL(k6_head, dim3(1), dim3(640), 0, stream, ws + OFF_FEAT,
                       c3w, c3b, bng, bnb, fcw, fcb, out);
}